// Round 3
// baseline (260.675 us; speedup 1.0000x reference)
//
#include <hip/hip_runtime.h>

// (1/sqrt(3)) * log2(e): folds softmax scale AND exp->exp2 into q.
// Softmax is shift-invariant; scores are O(+-4) -> no max-subtraction needed
// in fp32 (validated in rounds 1-2: identical math passed absmax check).
#define QSCALE 0.83294038f

// Interleaved K|V rows: row k of group g = 12 floats [K0..5, V0..5] at
// g*GSTRIDE + k*12. GSTRIDE=196 (16*12 + 4 pad): group offsets land on
// disjoint bank quads (196 mod 32 = 4) -> broadcast reads conflict-free.
#define GSTRIDE 196
#define WAVE_FLOATS 784        // 4 groups * 196
#define MAXBLOCKS 2048         // 8 blocks/CU * 256 CUs: fills once, no redispatch

__device__ __forceinline__ void proj6(const float* wp, const float* bp,
                                      float x0, float x1, float x2,
                                      float x3, float x4, float x5,
                                      float r[6])
{
    // wp = W + seg*36 (16B aligned), bp = b + seg*6 (8B aligned). L1-hot.
    float w[36];
    const float4* p = (const float4*)wp;
    #pragma unroll
    for (int i = 0; i < 9; ++i) {
        float4 v = p[i];
        w[i*4+0] = v.x; w[i*4+1] = v.y; w[i*4+2] = v.z; w[i*4+3] = v.w;
    }
    float bb[6];
    const float2* b2 = (const float2*)bp;
    #pragma unroll
    for (int i = 0; i < 3; ++i) { float2 v = b2[i]; bb[i*2] = v.x; bb[i*2+1] = v.y; }
    #pragma unroll
    for (int j = 0; j < 6; ++j) {
        r[j] = bb[j] + x0*w[j*6+0] + x1*w[j*6+1] + x2*w[j*6+2]
                     + x3*w[j*6+3] + x4*w[j*6+4] + x5*w[j*6+5];
    }
}

__global__ __launch_bounds__(256) void attn_seg_kernel(
    const float* __restrict__ x,
    const float* __restrict__ Wq, const float* __restrict__ bq,
    const float* __restrict__ Wk, const float* __restrict__ bk,
    const float* __restrict__ Wv, const float* __restrict__ bv,
    const float* __restrict__ Wo, const float* __restrict__ bo,
    float* __restrict__ out, int total)
{
    __shared__ __align__(16) float lds[4 * WAVE_FLOATS];   // 12.25 KB
    const int t   = threadIdx.x;
    const int wv_ = t >> 6;        // wave in block
    const int g   = (t >> 4) & 3;  // 16-lane group = one batch elem
    const int s   = t & 15;        // sequence position
    // SEG = [0, 1*5, 2*3, 3, 4*6]
    const int seg = (s == 0) ? 0 : (s < 6) ? 1 : (s < 9) ? 2 : (s == 9) ? 3 : 4;

    float* const kvg = &lds[wv_ * WAVE_FLOATS + g * GSTRIDE];  // group base
    float* const kvw = kvg + s * 12;                           // my row

    // per-lane weight bases; seg is fixed for the whole kernel
    const float* const wqb = Wq + seg * 36;
    const float* const wkb = Wk + seg * 36;
    const float* const wvb = Wv + seg * 36;
    const float* const bqb = bq + seg * 6;
    const float* const bkb = bk + seg * 6;
    const float* const bvb = bv + seg * 6;

    const int ntiles = (total + 255) >> 8;

    int tile = blockIdx.x;
    // prologue: x for first tile
    float x0=0.f,x1=0.f,x2=0.f,x3=0.f,x4=0.f,x5=0.f;
    {
        const int pos = (tile << 8) + t;
        if (pos < total) {
            const float* xp = x + (size_t)pos * 6;
            float2 a = *(const float2*)(xp);
            float2 b = *(const float2*)(xp + 2);
            float2 c = *(const float2*)(xp + 4);
            x0=a.x; x1=a.y; x2=b.x; x3=b.y; x4=c.x; x5=c.y;
        }
    }

    #pragma unroll 1
    for (; tile < ntiles; ) {
        const int pos   = (tile << 8) + t;
        const bool valid = pos < total;
        const int ntile = tile + gridDim.x;

        // ---- prefetch next tile's x (hides HBM under this tile's compute) ----
        float nx0=0.f,nx1=0.f,nx2=0.f,nx3=0.f,nx4=0.f,nx5=0.f;
        if (ntile < ntiles) {
            const int npos = (ntile << 8) + t;
            if (npos < total) {
                const float* xp = x + (size_t)npos * 6;
                float2 a = *(const float2*)(xp);
                float2 b = *(const float2*)(xp + 2);
                float2 c = *(const float2*)(xp + 4);
                nx0=a.x; nx1=a.y; nx2=b.x; nx3=b.y; nx4=c.x; nx5=c.y;
            }
        }

        // ---- projections; launder pointers so LICM can't hoist 126 floats ----
        float kk[6], vvv[6], q[6];
        {
            const float* wp = wkb; const float* bp = bkb;
            asm volatile("" : "+v"(wp), "+v"(bp));
            proj6(wp, bp, x0,x1,x2,x3,x4,x5, kk);
        }
        {
            const float* wp = wvb; const float* bp = bvb;
            asm volatile("" : "+v"(wp), "+v"(bp));
            proj6(wp, bp, x0,x1,x2,x3,x4,x5, vvv);
        }
        {
            const float* wp = wqb; const float* bp = bqb;
            asm volatile("" : "+v"(wp), "+v"(bp));
            proj6(wp, bp, x0,x1,x2,x3,x4,x5, q);
        }
        #pragma unroll
        for (int i = 0; i < 6; ++i) q[i] *= QSCALE;

        // ---- publish interleaved K|V row (3x b128; producer = this wave) ----
        *(float4*)(kvw)     = make_float4(kk[0], kk[1], kk[2], kk[3]);
        *(float4*)(kvw + 4) = make_float4(kk[4], kk[5], vvv[0], vvv[1]);
        *(float4*)(kvw + 8) = make_float4(vvv[2], vvv[3], vvv[4], vvv[5]);

        // wave-internal visibility only: drain LDS, pin ordering
        __builtin_amdgcn_wave_barrier();
        asm volatile("s_waitcnt lgkmcnt(0)" ::: "memory");
        __builtin_amdgcn_sched_barrier(0);

        // ---- fused scores -> exp2 -> sum -> PV (broadcast reads, e transient)
        float s0 = 0.f, s1 = 0.f;
        float c0=0.f,c1=0.f,c2=0.f,c3=0.f,c4=0.f,c5=0.f;
        #pragma unroll
        for (int k = 0; k < 16; ++k) {
            float4 a = *(const float4*)(kvg + k * 12);      // K0..K3
            float4 b = *(const float4*)(kvg + k * 12 + 4);  // K4,K5,V0,V1
            float4 c = *(const float4*)(kvg + k * 12 + 8);  // V2..V5
            float e0 = __builtin_amdgcn_exp2f(q[0]*a.x + q[1]*a.y + q[2]*a.z);
            float e1 = __builtin_amdgcn_exp2f(q[3]*a.w + q[4]*b.x + q[5]*b.y);
            s0 += e0; s1 += e1;
            c0 += e0*b.z; c1 += e0*b.w; c2 += e0*c.x;
            c3 += e1*c.y; c4 += e1*c.z; c5 += e1*c.w;
        }
        const float i0 = __builtin_amdgcn_rcpf(s0);
        const float i1 = __builtin_amdgcn_rcpf(s1);
        c0 *= i0; c1 *= i0; c2 *= i0;
        c3 *= i1; c4 *= i1; c5 *= i1;

        // ---- output projection: Wo,bo wave-uniform -> SGPR operands ----
        float o_[6];
        #pragma unroll
        for (int i = 0; i < 6; ++i) {
            o_[i] = bo[i] + c0*Wo[i*6+0] + c1*Wo[i*6+1] + c2*Wo[i*6+2]
                          + c3*Wo[i*6+3] + c4*Wo[i*6+4] + c5*Wo[i*6+5];
        }
        if (valid) {
            float* op = out + (size_t)pos * 6;
            *(float2*)(op)     = make_float2(o_[0], o_[1]);
            *(float2*)(op + 2) = make_float2(o_[2], o_[3]);
            *(float2*)(op + 4) = make_float2(o_[4], o_[5]);
        }

        // next iteration's ds_writes overwrite rows read above: same-wave DS is
        // in-order and reads' results are consumed; barrier pins compiler order.
        __builtin_amdgcn_wave_barrier();

        x0=nx0; x1=nx1; x2=nx2; x3=nx3; x4=nx4; x5=nx5;
        tile = ntile;
    }
}

extern "C" void kernel_launch(void* const* d_in, const int* in_sizes, int n_in,
                              void* d_out, int out_size, void* d_ws, size_t ws_size,
                              hipStream_t stream) {
    const float* x  = (const float*)d_in[0];
    const float* Wq = (const float*)d_in[1];
    const float* bq = (const float*)d_in[2];
    const float* Wk = (const float*)d_in[3];
    const float* bk = (const float*)d_in[4];
    const float* Wv = (const float*)d_in[5];
    const float* bv = (const float*)d_in[6];
    const float* Wo = (const float*)d_in[7];
    const float* bo = (const float*)d_in[8];
    float* out = (float*)d_out;

    const int total  = in_sizes[0] / 6;            // B*16 positions
    const int ntiles = (total + 255) / 256;
    const int grid   = ntiles < MAXBLOCKS ? ntiles : MAXBLOCKS;
    attn_seg_kernel<<<grid, 256, 0, stream>>>(x, Wq, bq, Wk, bk, Wv, bv, Wo, bo, out, total);
}